// Round 6
// baseline (156.412 us; speedup 1.0000x reference)
//
#include <hip/hip_runtime.h>

// Conv3d(8->32, k=3, VALID) + bias + HardSwish + GroupNorm(4) + mean pool.
// R6: B fragment = ONE aligned ds_read_b128. Tap grouping: chunk c in 0..6 uses
// tap tau = 4c + kq (each k-octet kq has its own tap); within an octet,
// k = 8kq + 2*cipair + parity. LDS tile [row 36][x 50][cipair 4] dwords ->
// lane's 4 B dwords are the 4 ci-pairs at one (row, x+kw): contiguous, 16B
// aligned, conflict-free without swizzle. 7 b128 + 28 MFMA per (y,nt) (was
// 28 b32 + 28 MFMA). Accs cut to 2 chains (hi chained after lo) = 8 AGPRs;
// launch_bounds(256,3) bids for 3 waves/SIMD (watch WRITE_SIZE for spill).

#define IN 48
#define IN2 2304
#define IN3 110592
#define OUTD 46
#define RS 200            // row stride in dwords = 50 x-slots * 4 ci-pairs
#define WPK_OFF 1024      // dword offset of packed-weight table inside ws

typedef short v8s   __attribute__((ext_vector_type(8)));
typedef float f32x4 __attribute__((ext_vector_type(4)));
typedef int   i32x4 __attribute__((ext_vector_type(4)));

__device__ __forceinline__ unsigned short f2bf(float f) {
    unsigned u = __builtin_bit_cast(unsigned, f);
    return (unsigned short)((u + 0x7fffu + ((u >> 16) & 1u)) >> 16);   // RNE
}
__device__ __forceinline__ float bf2f(unsigned short h) {
    unsigned u = ((unsigned)h) << 16;
    return __builtin_bit_cast(float, u);
}

// One-time: lane-exact A fragments. [hh=2h+hl][c 0..6][lane][4 dw].
// Lane (n,kq), chunk c: tau = 4c+kq; dword j holds (lo16: w[co][2j][tau],
// hi16: w[co][2j+1][tau]); tau >= 27 -> zeros (pad slot).
__global__ __launch_bounds__(256) void pack_weights(
    const float* __restrict__ w, unsigned* __restrict__ wpk)
{
    int gid = blockIdx.x * 256 + threadIdx.x;
    if (gid >= 1792) return;
    int lane = gid & 63;
    int rest = gid >> 6;
    int c  = rest % 7;
    int hh = rest / 7;
    int h  = hh >> 1, hl = hh & 1;
    int n  = lane & 15, kq = lane >> 4;
    int co = h * 16 + n;
    int tau = 4 * c + kq;
    unsigned o[4];
    #pragma unroll
    for (int j = 0; j < 4; ++j) {
        if (tau >= 27) { o[j] = 0u; continue; }
        float w0 = w[(co * 8 + 2 * j) * 27 + tau];
        float w1 = w[(co * 8 + 2 * j + 1) * 27 + tau];
        unsigned short b0 = f2bf(w0), b1 = f2bf(w1);
        if (hl) {
            b0 = f2bf(w0 - bf2f(b0));
            b1 = f2bf(w1 - bf2f(b1));
        }
        o[j] = ((unsigned)b1 << 16) | b0;
    }
    *(i32x4*)(wpk + ((hh * 7 + c) * 64 + lane) * 4) =
        (i32x4){(int)o[0], (int)o[1], (int)o[2], (int)o[3]};
}

__global__ __launch_bounds__(256, 3) void conv_hs_mfma(
    const float* __restrict__ x, const unsigned* __restrict__ wpk,
    const float* __restrict__ bias, float* __restrict__ ws1, float* __restrict__ ws2)
{
    __shared__ unsigned xdw[36 * RS];   // 28.8 KB: [row 36][x 50][cipair 4]
    __shared__ float s1b[32], s2b[32];

    const int tid  = threadIdx.x;
    const int lane = tid & 63;
    const int wv   = tid >> 6;          // wave id = z offset within tile
    const int n    = lane & 15;         // MFMA A-row (co) / B-col index
    const int kq   = lane >> 4;         // k-octet

    const int blk = blockIdx.x;
    const int b   = blk / 144;
    const int r0  = blk - b * 144;
    const int zb  = r0 / 12;
    const int yb  = r0 - zb * 12;
    const int z0  = zb * 4, y0 = yb * 4;
    const int z   = z0 + wv;

    if (tid < 32) { s1b[tid] = 0.f; s2b[tid] = 0.f; }

    // A fragments: 28 coalesced 16B loads from the precomputed table.
    i32x4 Ah[2][7], Al[2][7];
    #pragma unroll
    for (int h = 0; h < 2; ++h)
        #pragma unroll
        for (int c = 0; c < 7; ++c) {
            Ah[h][c] = *(const i32x4*)(wpk + (((h * 2 + 0) * 7 + c) * 64 + lane) * 4);
            Al[h][c] = *(const i32x4*)(wpk + (((h * 2 + 1) * 7 + c) * 64 + lane) * 4);
        }

    // Per-lane B-address deltas (dwords) for each chunk: tap tau = 4c + kq.
    // Pad (tau>=27) -> tap (0,0,0): in-bounds read, A=0 annihilates it.
    int del[7];
    #pragma unroll
    for (int c = 0; c < 7; ++c) {
        int tau = 4 * c + kq;
        if (tau > 26) tau = 0;
        int kd = tau / 9, r = tau % 9;
        del[c] = (kd * 6 + r / 3) * RS + (r % 3) * 4;
    }

    // C/D layout: row(co) = kq*4 + i (+16h), col = n
    float bias_r[8];
    #pragma unroll
    for (int h = 0; h < 2; ++h)
        #pragma unroll
        for (int i = 0; i < 4; ++i)
            bias_r[h * 4 + i] = bias[h * 16 + kq * 4 + i];

    // ---- stage x tile: dword [row][e][q] = bf16(ci 2q+1)<<16 | bf16(ci 2q) ----
    {
        const int q = tid & 3;
        const int e = tid >> 2;            // 0..63, stage e<50 (x 48,49 are read-pad)
        if (e < 50) {
            const int gx = min(e, IN - 1);
            const float* p0 = x + (b * 8 + 2 * q) * IN3 + gx;
            const float* p1 = p0 + IN3;
            unsigned* dst = xdw + e * 4 + q;
            #pragma unroll
            for (int zr = 0; zr < 6; ++zr) {
                const int gz = min(z0 + zr, IN - 1);
                #pragma unroll
                for (int yr = 0; yr < 6; ++yr) {
                    const int gy = min(y0 + yr, IN - 1);
                    const int off = gz * IN2 + gy * IN;
                    float f0 = p0[off], f1 = p1[off];
                    dst[(zr * 6 + yr) * RS] = ((unsigned)f2bf(f1) << 16) | f2bf(f0);
                }
            }
        }
    }
    __syncthreads();

    float t1[8] = {0, 0, 0, 0, 0, 0, 0, 0};
    float t2[8] = {0, 0, 0, 0, 0, 0, 0, 0};

    if (z < OUTD) {
        const int ymax = min(4, OUTD - y0);
        for (int y = 0; y < ymax; ++y) {
            #pragma unroll
            for (int nt = 0; nt < 3; ++nt) {
                const int col = nt * 16 + n;
                const unsigned* yp = xdw + (wv * 6 + y) * RS + col * 4;
                f32x4 a0 = {0, 0, 0, 0}, a1 = {0, 0, 0, 0};
                #pragma unroll
                for (int c = 0; c < 7; ++c) {
                    i32x4 bd = *(const i32x4*)(yp + del[c]);   // one ds_read_b128
                    v8s B = __builtin_bit_cast(v8s, bd);
                    a0 = __builtin_amdgcn_mfma_f32_16x16x32_bf16(__builtin_bit_cast(v8s, Al[0][c]), B, a0, 0, 0, 0);
                    a0 = __builtin_amdgcn_mfma_f32_16x16x32_bf16(__builtin_bit_cast(v8s, Ah[0][c]), B, a0, 0, 0, 0);
                    a1 = __builtin_amdgcn_mfma_f32_16x16x32_bf16(__builtin_bit_cast(v8s, Al[1][c]), B, a1, 0, 0, 0);
                    a1 = __builtin_amdgcn_mfma_f32_16x16x32_bf16(__builtin_bit_cast(v8s, Ah[1][c]), B, a1, 0, 0, 0);
                }
                #pragma unroll
                for (int h = 0; h < 2; ++h) {
                    #pragma unroll
                    for (int i = 0; i < 4; ++i) {
                        float v = (h ? a1[i] : a0[i]) + bias_r[h * 4 + i];
                        float u = fminf(fmaxf(v + 3.0f, 0.0f), 6.0f);
                        float hs = v * u * (1.0f / 6.0f);
                        if (nt == 2) hs = (col < OUTD) ? hs : 0.f;   // only tile 2 straddles
                        t1[h * 4 + i] += hs;
                        t2[h * 4 + i] = fmaf(hs, hs, t2[h * 4 + i]);
                    }
                }
            }
        }
    }

    // reduce over the 16 col-lanes (n); channel set is per-(kq,h,i)
    #pragma unroll
    for (int j = 0; j < 8; ++j) {
        #pragma unroll
        for (int k = 1; k < 16; k <<= 1) {
            t1[j] += __shfl_xor(t1[j], k, 64);
            t2[j] += __shfl_xor(t2[j], k, 64);
        }
    }
    if (n == 0) {
        #pragma unroll
        for (int h = 0; h < 2; ++h)
            #pragma unroll
            for (int i = 0; i < 4; ++i) {
                atomicAdd(&s1b[h * 16 + kq * 4 + i], t1[h * 4 + i]);
                atomicAdd(&s2b[h * 16 + kq * 4 + i], t2[h * 4 + i]);
            }
    }
    __syncthreads();
    if (tid < 32)       atomicAdd(&ws1[b * 32 + tid], s1b[tid]);
    else if (tid < 64)  atomicAdd(&ws2[b * 32 + (tid - 32)], s2b[tid - 32]);
}

__global__ __launch_bounds__(512) void gn_finalize(
    const float* __restrict__ ws1, const float* __restrict__ ws2,
    const float* __restrict__ gnw, const float* __restrict__ gnb,
    float* __restrict__ out)
{
    int tid = threadIdx.x;
    int c = tid & 31;
    float s1 = ws1[tid], s2 = ws2[tid];
    float g1 = s1, g2 = s2;
    #pragma unroll
    for (int k = 1; k < 8; k <<= 1) {
        g1 += __shfl_xor(g1, k, 64);
        g2 += __shfl_xor(g2, k, 64);
    }
    const float Nsp  = 46.0f * 46.0f * 46.0f;
    const float invN = 1.0f / (8.0f * Nsp);
    float mean = g1 * invN;
    float var  = fmaxf(g2 * invN - mean * mean, 0.0f);
    float rstd = rsqrtf(var + 1e-5f);
    float mc   = s1 * (1.0f / Nsp);
    out[tid] = (mc - mean) * rstd * gnw[c] + gnb[c];
}

extern "C" void kernel_launch(void* const* d_in, const int* in_sizes, int n_in,
                              void* d_out, int out_size, void* d_ws, size_t ws_size,
                              hipStream_t stream) {
    const float* x    = (const float*)d_in[0];
    const float* w    = (const float*)d_in[1];
    const float* bias = (const float*)d_in[2];
    const float* gnw  = (const float*)d_in[3];
    const float* gnb  = (const float*)d_in[4];
    float* out = (float*)d_out;
    float* ws1 = (float*)d_ws;
    float* ws2 = ws1 + 512;
    unsigned* wpk = (unsigned*)d_ws + WPK_OFF;   // 7168 dwords

    hipMemsetAsync(d_ws, 0, 1024 * sizeof(float), stream);
    pack_weights<<<dim3(7), dim3(256), 0, stream>>>(w, wpk);
    conv_hs_mfma<<<dim3(16 * 12 * 12), dim3(256), 0, stream>>>(x, wpk, bias, ws1, ws2);
    gn_finalize<<<dim3(1), dim3(512), 0, stream>>>(ws1, ws2, gnw, gnb, out);
}